// Round 4
// baseline (291.104 us; speedup 1.0000x reference)
//
#include <hip/hip_runtime.h>

// Problem constants (fixed by reference)
constexpr int Bn = 4, Cn = 64, Hn = 192, Wn = 640, HW = Hn * Wn;
constexpr int TW = 64, TH = 16;           // output tile per block
constexpr int SW = TW + 4, SH = TH + 4;   // 68 x 20 tile+halo
constexpr int NS = SW * SH;               // 1360 words
constexpr int NP = NS / 2;                // 680 float2 pairs
constexpr int PPR = SW / 2;               // 34 pairs per row
constexpr int NT = 256;                   // 16 thr-x (4 px each) x 16 thr-y
constexpr int CH = 2;                     // channels per chunk
constexpr int NCHUNK = Cn / CH;           // 32

__global__ __launch_bounds__(NT, 3) void guide_triplet_kernel(
    const float* __restrict__ pred,
    const int*   __restrict__ target,
    float* __restrict__ out)
{
    __shared__ alignas(16) float slice[2][CH][NS];  // 21.8 KB double-buffered
    __shared__ float invnS[NS];
    __shared__ int   lblS[NS];

    const int x0 = blockIdx.x * TW;
    const int y0 = blockIdx.y * TH;
    const int b  = blockIdx.z;

    const int tid = threadIdx.x;
    const int tx  = tid & 15;    // 0..15 -> output cols x0+4tx .. +3
    const int ty  = tid >> 4;    // 0..15 -> output row  y0+ty

    // ---- pair-staging geometry (halo=2 == pair width -> pairs all-in/all-out)
    int goff[3]; bool okp[3]; bool has[3]; int pp[3];
    #pragma unroll
    for (int j = 0; j < 3; ++j) {
        const int p = tid + NT * j;
        pp[j] = p;
        const int row = p / PPR, pc = p - row * PPR;
        const int gy = y0 + row - 2, gx = x0 + 2 * pc - 2;
        has[j]  = (p < NP);
        okp[j]  = has[j] && (gy >= 0) && (gy < Hn) && (gx >= 0) && (gx + 1 < Wn);
        goff[j] = gy * Wn + gx;
    }

    // ---- labels once (pad = -1), int2 loads
    {
        const int* tb = target + b * HW;
        #pragma unroll
        for (int j = 0; j < 3; ++j) if (has[j]) {
            int lx = -1, ly = -1;
            if (okp[j]) { const int2 L = *reinterpret_cast<const int2*>(tb + goff[j]); lx = L.x; ly = L.y; }
            lblS[2 * pp[j]]     = lx;
            lblS[2 * pp[j] + 1] = ly;
        }
    }

    float ssx[3] = {0.f, 0.f, 0.f}, ssy[3] = {0.f, 0.f, 0.f};
    float acc0[25], acc1[25], acc2[25], acc3[25];
    #pragma unroll
    for (int i = 0; i < 25; ++i) { acc0[i] = 0.f; acc1[i] = 0.f; acc2[i] = 0.f; acc3[i] = 0.f; }

    const float* predb = pred + (size_t)b * Cn * HW;

    float2 ldA[CH][3], ldB[CH][3];

#define LOADCHUNK(DST, CHUNK) do {                                              \
    _Pragma("unroll")                                                           \
    for (int cc = 0; cc < CH; ++cc) {                                           \
        const float* pc_ = predb + (size_t)((CHUNK) * CH + cc) * HW;            \
        _Pragma("unroll")                                                       \
        for (int j = 0; j < 3; ++j) {                                           \
            float2 v = make_float2(0.f, 0.f);                                   \
            if (okp[j]) v = *reinterpret_cast<const float2*>(pc_ + goff[j]);    \
            DST[cc][j] = v;                                                     \
        } } } while (0)

    LOADCHUNK(ldA, 0);
    LOADCHUNK(ldB, 1);

#define ROWFMA(ACC, CQ, R, W0, W1, W2, W3, W4)                                  \
    ACC[5*(R)+0] = fmaf(CQ, W0, ACC[5*(R)+0]);                                  \
    ACC[5*(R)+1] = fmaf(CQ, W1, ACC[5*(R)+1]);                                  \
    ACC[5*(R)+2] = fmaf(CQ, W2, ACC[5*(R)+2]);                                  \
    ACC[5*(R)+3] = fmaf(CQ, W3, ACC[5*(R)+3]);                                  \
    ACC[5*(R)+4] = fmaf(CQ, W4, ACC[5*(R)+4]);

#define DOROW(R) {                                                              \
    const float4 A_ = *reinterpret_cast<const float4*>(sc + (R)*SW);            \
    const float4 B_ = *reinterpret_cast<const float4*>(sc + (R)*SW + 4);        \
    const float w0=A_.x, w1=A_.y, w2=A_.z, w3=A_.w;                             \
    const float w4=B_.x, w5=B_.y, w6=B_.z, w7=B_.w;                             \
    ROWFMA(acc0, c0, R, w0, w1, w2, w3, w4)                                     \
    ROWFMA(acc1, c1, R, w1, w2, w3, w4, w5)                                     \
    ROWFMA(acc2, c2, R, w2, w3, w4, w5, w6)                                     \
    ROWFMA(acc3, c3, R, w3, w4, w5, w6, w7) }

#define BODY(K, LD) {                                                           \
    float (*sb)[NS] = slice[(K) & 1];                                           \
    /* W(K): regs -> LDS (b64 writes), fold sumsq */                            \
    _Pragma("unroll")                                                           \
    for (int cc = 0; cc < CH; ++cc) {                                           \
        _Pragma("unroll")                                                       \
        for (int j = 0; j < 3; ++j) if (has[j]) {                               \
            const float2 v = LD[cc][j];                                         \
            *reinterpret_cast<float2*>(&sb[cc][2 * pp[j]]) = v;                 \
            ssx[j] = fmaf(v.x, v.x, ssx[j]);                                    \
            ssy[j] = fmaf(v.y, v.y, ssy[j]);                                    \
        } }                                                                     \
    __syncthreads();                                                            \
    /* L(K+2): issue 2-chunks-ahead loads; latency hides under C(K),C(K+1) */   \
    if ((K) + 2 < NCHUNK) LOADCHUNK(LD, (K) + 2);                               \
    /* C(K): 10 ds_read_b128 + 100 FMA per channel */                           \
    _Pragma("unroll")                                                           \
    for (int cc = 0; cc < CH; ++cc) {                                           \
        const float* sc = &sb[cc][0] + ty * SW + 4 * tx;                        \
        const float4 A2 = *reinterpret_cast<const float4*>(sc + 2*SW);          \
        const float4 B2 = *reinterpret_cast<const float4*>(sc + 2*SW + 4);      \
        const float w0=A2.x, w1=A2.y, w2=A2.z, w3=A2.w;                         \
        const float w4=B2.x, w5=B2.y, w6=B2.z, w7=B2.w;                         \
        const float c0=w2, c1=w3, c2=w4, c3=w5;                                 \
        ROWFMA(acc0, c0, 2, w0, w1, w2, w3, w4)                                 \
        ROWFMA(acc1, c1, 2, w1, w2, w3, w4, w5)                                 \
        ROWFMA(acc2, c2, 2, w2, w3, w4, w5, w6)                                 \
        ROWFMA(acc3, c3, 2, w3, w4, w5, w6, w7)                                 \
        DOROW(0) DOROW(1) DOROW(3) DOROW(4)                                     \
    } }

    for (int chunk = 0; chunk < NCHUNK; chunk += 2) {
        BODY(chunk,     ldA)
        BODY(chunk + 1, ldB)
    }

    // ---- inverse norms
    #pragma unroll
    for (int j = 0; j < 3; ++j) if (has[j]) {
        invnS[2 * pp[j]]     = 1.0f / fmaxf(sqrtf(ssx[j]), 1e-12f);
        invnS[2 * pp[j] + 1] = 1.0f / fmaxf(sqrtf(ssy[j]), 1e-12f);
    }
    __syncthreads();

    // ---- epilogue: triplet margin, all static indices
    const int ebase = ty * SW + 4 * tx;
    float res[4];
#define EPI(Q, ACC) {                                                           \
    const float ic = invnS[ebase + 2 * SW + 2 + (Q)];                           \
    const int   lc = lblS [ebase + 2 * SW + 2 + (Q)];                           \
    float pn = 0.f, nn = 0.f, ps = 0.f, ns = 0.f;                               \
    _Pragma("unroll")                                                           \
    for (int r = 0; r < 5; ++r) {                                               \
        _Pragma("unroll")                                                       \
        for (int dj = 0; dj < 5; ++dj) {                                        \
            const int e = ebase + r * SW + (Q) + dj;                            \
            const float sim = ACC[5*r+dj] * ic * invnS[e];                      \
            const float aff = sqrtf(fmaxf(1e-9f, 2.0f - 2.0f * sim));           \
            const float mf  = (lblS[e] == lc) ? 1.0f : 0.0f;                    \
            pn += mf; nn += 1.0f - mf;                                          \
            ps = fmaf(mf, aff, ps); ns = fmaf(1.0f - mf, aff, ns);              \
        } }                                                                     \
    const bool  bd = (pn >= 4.0f) && (nn >= 4.0f);                              \
    const float tr = fmaxf(0.0f, ps / pn - ns / fmaxf(nn, 1e-12f) + 0.3f);     \
    res[Q] = bd ? tr : 0.0f; }

    EPI(0, acc0) EPI(1, acc1) EPI(2, acc2) EPI(3, acc3)

    *reinterpret_cast<float4*>(&out[((size_t)b * Hn + (y0 + ty)) * Wn + x0 + 4 * tx]) =
        make_float4(res[0], res[1], res[2], res[3]);
}

extern "C" void kernel_launch(void* const* d_in, const int* in_sizes, int n_in,
                              void* d_out, int out_size, void* d_ws, size_t ws_size,
                              hipStream_t stream) {
    const float* pred   = (const float*)d_in[0];
    const int*   target = (const int*)d_in[1];
    float*       out    = (float*)d_out;
    dim3 grid(Wn / TW, Hn / TH, Bn);   // 10 x 12 x 4 = 480 blocks
    guide_triplet_kernel<<<grid, NT, 0, stream>>>(pred, target, out);
}

// Round 5
// 161.644 us; speedup vs baseline: 1.8009x; 1.8009x over previous
//
#include <hip/hip_runtime.h>

// Problem constants (fixed by reference)
constexpr int Bn = 4, Cn = 64, Hn = 192, Wn = 640, HW = Hn * Wn;
constexpr int TW = 64, TH = 8;            // output tile per block
constexpr int SW = TW + 4, SH = TH + 4;   // 68 x 12 tile+halo
constexpr int NS = SW * SH;               // 816 words
constexpr int NP = NS / 2;                // 408 float2 pairs
constexpr int PPR = SW / 2;               // 34 pairs per row
constexpr int NT = 256;                   // 32 thr-x (2 px each) x 8 thr-y
constexpr int CH = 2;                     // channels per chunk
constexpr int NCHUNK = Cn / CH;           // 32

__global__ __launch_bounds__(NT, 4) void guide_triplet_kernel(
    const float* __restrict__ pred,
    const int*   __restrict__ target,
    float* __restrict__ out)
{
    // 13 KB double-buffered slices; epilogue aliases invn/lbl into slice[0]
    __shared__ alignas(16) float slice[2][CH][NS];

    const int x0 = blockIdx.x * TW;
    const int y0 = blockIdx.y * TH;
    const int b  = blockIdx.z;

    const int tid = threadIdx.x;
    const int tx  = tid & 31;    // 0..31 -> output cols x0+2tx, x0+2tx+1
    const int ty  = tid >> 5;    // 0..7  -> output row  y0+ty

    // ---- pair staging geometry (halo=2 == pair width -> pairs all-in/all-out)
    const int p0 = tid, p1 = tid + NT;
    const bool has1 = (p1 < NP);             // tid < 152
    const int row0 = p0 / PPR, pc0 = p0 - row0 * PPR;
    const int row1 = p1 / PPR, pc1 = p1 - row1 * PPR;
    const int gy0 = y0 + row0 - 2, gx0 = x0 + 2 * pc0 - 2;
    const int gy1 = y0 + row1 - 2, gx1 = x0 + 2 * pc1 - 2;
    const bool ok0 = (gy0 >= 0) && (gy0 < Hn) && (gx0 >= 0) && (gx0 + 1 < Wn);
    const bool ok1 = has1 && (gy1 >= 0) && (gy1 < Hn) && (gx1 >= 0) && (gx1 + 1 < Wn);
    const int goff0 = gy0 * Wn + gx0;
    const int goff1 = gy1 * Wn + gx1;

    float ssx0 = 0.f, ssy0 = 0.f, ssx1 = 0.f, ssy1 = 0.f;
    float acc0[25], acc1[25];
    #pragma unroll
    for (int i = 0; i < 25; ++i) { acc0[i] = 0.f; acc1[i] = 0.f; }

    const float* predb = pred + (size_t)b * Cn * HW;

    float2 ldA[CH][2], ldB[CH][2];

#define LOADCHUNK(DST, CHUNK) do {                                              \
    _Pragma("unroll")                                                           \
    for (int cc = 0; cc < CH; ++cc) {                                           \
        const float* pc_ = predb + (size_t)((CHUNK) * CH + cc) * HW;            \
        float2 v0 = make_float2(0.f, 0.f), v1 = make_float2(0.f, 0.f);          \
        if (ok0) v0 = *reinterpret_cast<const float2*>(pc_ + goff0);            \
        if (ok1) v1 = *reinterpret_cast<const float2*>(pc_ + goff1);            \
        DST[cc][0] = v0; DST[cc][1] = v1;                                       \
    } } while (0)

    LOADCHUNK(ldA, 0);
    LOADCHUNK(ldB, 1);

#define BODY(K, LD) {                                                           \
    float (*sb)[NS] = slice[(K) & 1];                                           \
    /* W(K): regs -> LDS (b64 writes), fold sumsq */                            \
    _Pragma("unroll")                                                           \
    for (int cc = 0; cc < CH; ++cc) {                                           \
        const float2 v0 = LD[cc][0];                                            \
        *reinterpret_cast<float2*>(&sb[cc][2 * p0]) = v0;                       \
        ssx0 = fmaf(v0.x, v0.x, ssx0);                                          \
        ssy0 = fmaf(v0.y, v0.y, ssy0);                                          \
        if (has1) {                                                             \
            const float2 v1 = LD[cc][1];                                        \
            *reinterpret_cast<float2*>(&sb[cc][2 * p1]) = v1;                   \
            ssx1 = fmaf(v1.x, v1.x, ssx1);                                      \
            ssy1 = fmaf(v1.y, v1.y, ssy1);                                      \
        } }                                                                     \
    __syncthreads();                                                            \
    /* L(K+2): issue loads 2 chunks ahead; latency hides under C(K),C(K+1) */   \
    if ((K) + 2 < NCHUNK) LOADCHUNK(LD, (K) + 2);                               \
    /* C(K): per channel 15 ds_read_b64 + 50 FMA (2 px) */                      \
    _Pragma("unroll")                                                           \
    for (int cc = 0; cc < CH; ++cc) {                                           \
        const float* sc = &sb[cc][ty * SW + 2 * tx];                            \
        const float2 m0 = *reinterpret_cast<const float2*>(sc + 2 * SW);        \
        const float2 m1 = *reinterpret_cast<const float2*>(sc + 2 * SW + 2);    \
        const float2 m2 = *reinterpret_cast<const float2*>(sc + 2 * SW + 4);    \
        const float c0 = m1.x, c1 = m1.y;                                       \
        /* row 2 (reuse m-loads) */                                             \
        acc0[10] = fmaf(c0, m0.x, acc0[10]); acc1[10] = fmaf(c1, m0.y, acc1[10]);\
        acc0[11] = fmaf(c0, m0.y, acc0[11]); acc1[11] = fmaf(c1, m1.x, acc1[11]);\
        acc0[12] = fmaf(c0, m1.x, acc0[12]); acc1[12] = fmaf(c1, m1.y, acc1[12]);\
        acc0[13] = fmaf(c0, m1.y, acc0[13]); acc1[13] = fmaf(c1, m2.x, acc1[13]);\
        acc0[14] = fmaf(c0, m2.x, acc0[14]); acc1[14] = fmaf(c1, m2.y, acc1[14]);\
        _Pragma("unroll")                                                       \
        for (int rr = 0; rr < 4; ++rr) {                                        \
            const int r = (rr < 2) ? rr : rr + 1;   /* 0,1,3,4 const-folded */  \
            const float2 a0 = *reinterpret_cast<const float2*>(sc + r * SW);    \
            const float2 a1 = *reinterpret_cast<const float2*>(sc + r * SW + 2);\
            const float2 a2 = *reinterpret_cast<const float2*>(sc + r * SW + 4);\
            acc0[5*r+0] = fmaf(c0, a0.x, acc0[5*r+0]);                          \
            acc0[5*r+1] = fmaf(c0, a0.y, acc0[5*r+1]);                          \
            acc0[5*r+2] = fmaf(c0, a1.x, acc0[5*r+2]);                          \
            acc0[5*r+3] = fmaf(c0, a1.y, acc0[5*r+3]);                          \
            acc0[5*r+4] = fmaf(c0, a2.x, acc0[5*r+4]);                          \
            acc1[5*r+0] = fmaf(c1, a0.y, acc1[5*r+0]);                          \
            acc1[5*r+1] = fmaf(c1, a1.x, acc1[5*r+1]);                          \
            acc1[5*r+2] = fmaf(c1, a1.y, acc1[5*r+2]);                          \
            acc1[5*r+3] = fmaf(c1, a2.x, acc1[5*r+3]);                          \
            acc1[5*r+4] = fmaf(c1, a2.y, acc1[5*r+4]);                          \
        } } }

    for (int chunk = 0; chunk < NCHUNK; chunk += 2) {
        BODY(chunk,     ldA)
        BODY(chunk + 1, ldB)
    }

    // ---- epilogue: alias invn/lbl into slice[0] (last compute reads slice[1])
    float* invnL = &slice[0][0][0];
    int*   lblL  = reinterpret_cast<int*>(&slice[0][1][0]);
    {
        const int* tb = target + b * HW;
        invnL[2 * p0]     = 1.0f / fmaxf(sqrtf(ssx0), 1e-12f);
        invnL[2 * p0 + 1] = 1.0f / fmaxf(sqrtf(ssy0), 1e-12f);
        int lx0 = -1, ly0 = -1;
        if (ok0) { const int2 L = *reinterpret_cast<const int2*>(tb + goff0); lx0 = L.x; ly0 = L.y; }
        lblL[2 * p0]     = lx0;
        lblL[2 * p0 + 1] = ly0;
        if (has1) {
            invnL[2 * p1]     = 1.0f / fmaxf(sqrtf(ssx1), 1e-12f);
            invnL[2 * p1 + 1] = 1.0f / fmaxf(sqrtf(ssy1), 1e-12f);
            int lx1 = -1, ly1 = -1;
            if (ok1) { const int2 L = *reinterpret_cast<const int2*>(tb + goff1); lx1 = L.x; ly1 = L.y; }
            lblL[2 * p1]     = lx1;
            lblL[2 * p1 + 1] = ly1;
        }
    }
    __syncthreads();

    // ---- triplet margin for the 2 owned pixels (all static indices)
    const int ebase = ty * SW + 2 * tx;
    float res0, res1;
#define EPI(Q, ACC, RES) {                                                      \
    const float ic = invnL[ebase + 2 * SW + 2 + (Q)];                           \
    const int   lc = lblL [ebase + 2 * SW + 2 + (Q)];                           \
    float pn = 0.f, nn = 0.f, ps = 0.f, ns = 0.f;                               \
    _Pragma("unroll")                                                           \
    for (int di = 0; di < 5; ++di) {                                            \
        _Pragma("unroll")                                                       \
        for (int dj = 0; dj < 5; ++dj) {                                        \
            const int e = ebase + di * SW + (Q) + dj;                           \
            const float sim = ACC[5*di+dj] * ic * invnL[e];                     \
            const float aff = sqrtf(fmaxf(1e-9f, 2.0f - 2.0f * sim));           \
            const float mf  = (lblL[e] == lc) ? 1.0f : 0.0f;                    \
            pn += mf; nn += 1.0f - mf;                                          \
            ps = fmaf(mf, aff, ps); ns = fmaf(1.0f - mf, aff, ns);              \
        } }                                                                     \
    const bool  bd = (pn >= 4.0f) && (nn >= 4.0f);                              \
    const float tr = fmaxf(0.0f, ps / pn - ns / fmaxf(nn, 1e-12f) + 0.3f);     \
    RES = bd ? tr : 0.0f; }

    EPI(0, acc0, res0)
    EPI(1, acc1, res1)

    *reinterpret_cast<float2*>(&out[((size_t)b * Hn + (y0 + ty)) * Wn + x0 + 2 * tx]) =
        make_float2(res0, res1);
}

extern "C" void kernel_launch(void* const* d_in, const int* in_sizes, int n_in,
                              void* d_out, int out_size, void* d_ws, size_t ws_size,
                              hipStream_t stream) {
    const float* pred   = (const float*)d_in[0];
    const int*   target = (const int*)d_in[1];
    float*       out    = (float*)d_out;
    dim3 grid(Wn / TW, Hn / TH, Bn);   // 10 x 24 x 4 = 960 blocks
    guide_triplet_kernel<<<grid, NT, 0, stream>>>(pred, target, out);
}

// Round 6
// 85.953 us; speedup vs baseline: 3.3868x; 1.8806x over previous
//
#include <hip/hip_runtime.h>

// Problem constants (fixed by reference)
constexpr int Bn = 4, Cn = 64, Hn = 192, Wn = 640, HW = Hn * Wn;
constexpr int TH = 8, TW = 64;            // output tile per block
constexpr int SH = TH + 4, SW = TW + 4;   // 12 x 68 tile+halo
constexpr int NS = SH * SW;               // 816
constexpr int NT = 512;                   // 1 px/thread
constexpr int CH = 4;                     // channels staged per chunk
constexpr int NCHUNK = Cn / CH;           // 16

__global__ __launch_bounds__(NT, 4) void guide_triplet_kernel(
    const float* __restrict__ pred,
    const int*   __restrict__ target,
    float* __restrict__ out)
{
    __shared__ float slice[2][CH][NS];   // double-buffered channel slices (26 KB)
    __shared__ float invnS[NS];
    __shared__ int   lblS[NS];

    const int x0 = blockIdx.x * TW;
    const int y0 = blockIdx.y * TH;
    const int b  = blockIdx.z;

    const int tid = threadIdx.x;
    const int tx  = tid & (TW - 1);   // 0..63
    const int ty  = tid >> 6;         // 0..7

    // staging geometry (2 elements/thread, 2nd partial)
    const int e0 = tid;
    const int e1 = tid + NT;
    const bool has1 = (e1 < NS);      // tid < 304
    const int r0 = e0 / SW, c0 = e0 % SW;
    const int r1 = e1 / SW, c1 = e1 % SW;
    const int gy0 = y0 + r0 - 2, gx0 = x0 + c0 - 2;
    const int gy1 = y0 + r1 - 2, gx1 = x0 + c1 - 2;
    const bool ok0 = (gy0 >= 0) && (gy0 < Hn) && (gx0 >= 0) && (gx0 < Wn);
    const bool ok1 = has1 && (gy1 >= 0) && (gy1 < Hn) && (gx1 >= 0) && (gx1 < Wn);
    const int off0 = gy0 * Wn + gx0;
    const int off1 = gy1 * Wn + gx1;

    // labels once (pad = -1)
    {
        const int* tb = target + b * HW;
        lblS[e0] = ok0 ? tb[off0] : -1;
        if (has1) lblS[e1] = ok1 ? tb[off1] : -1;
    }

    float ss0 = 0.0f, ss1 = 0.0f;
    float acc[25];
    #pragma unroll
    for (int i = 0; i < 25; ++i) acc[i] = 0.0f;

    const float* predb = pred + (size_t)b * Cn * HW;

    // Opaque row-4 word offset: forces a SEPARATE base VGPR for row-4 LDS
    // reads, so their read2 offsets are 0..4 (mergeable) instead of 272..276
    // (>255, unmergeable). One v_add per channel, ~2x fewer LDS instructions.
    int row4off = 4 * SW;
    asm volatile("" : "+v"(row4off));

    // prologue: chunk 0 into registers
    float ld0[CH], ld1[CH];
    #pragma unroll
    for (int cc = 0; cc < CH; ++cc) {
        ld0[cc] = ok0 ? predb[cc * HW + off0] : 0.0f;
        ld1[cc] = ok1 ? predb[cc * HW + off1] : 0.0f;
    }

    // main loop:  W(k) | sync | issue L(k+1) | C(k)
    for (int chunk = 0; chunk < NCHUNK; ++chunk) {
        float (*sb)[NS] = slice[chunk & 1];

        // W(k): registers -> LDS, fold sumsq
        #pragma unroll
        for (int cc = 0; cc < CH; ++cc) {
            sb[cc][e0] = ld0[cc];
            ss0 = fmaf(ld0[cc], ld0[cc], ss0);
            if (has1) {
                sb[cc][e1] = ld1[cc];
                ss1 = fmaf(ld1[cc], ld1[cc], ss1);
            }
        }
        __syncthreads();

        // L(k+1): issue next chunk's loads; latency hidden under C(k)
        if (chunk + 1 < NCHUNK) {
            const float* pc = predb + (size_t)(chunk + 1) * CH * HW;
            #pragma unroll
            for (int cc = 0; cc < CH; ++cc) {
                ld0[cc] = ok0 ? pc[cc * HW + off0] : 0.0f;
                ld1[cc] = ok1 ? pc[cc * HW + off1] : 0.0f;
            }
        }

        // C(k): 25 word reads -> ~13 ds_read2_b32 + 25 FMA per channel
        #pragma unroll
        for (int cc = 0; cc < CH; ++cc) {
            const float* sc  = &sb[cc][ty * SW + tx];
            const float* sc4 = sc + row4off;
            // row 2 first (center f = its dj=2 word; self-term = f*f)
            {
                const float v0 = sc[2 * SW + 0], v1 = sc[2 * SW + 1],
                            v2 = sc[2 * SW + 2], v3 = sc[2 * SW + 3],
                            v4 = sc[2 * SW + 4];
                const float f = v2;
                acc[10] = fmaf(f, v0, acc[10]);
                acc[11] = fmaf(f, v1, acc[11]);
                acc[12] = fmaf(f, v2, acc[12]);
                acc[13] = fmaf(f, v3, acc[13]);
                acc[14] = fmaf(f, v4, acc[14]);
                // rows 0,1,3,4 (4 -> opaque base)
                #pragma unroll
                for (int rr = 0; rr < 4; ++rr) {
                    const int r = (rr < 2) ? rr : rr + 1;          // 0,1,3,4
                    const float* sr = (r == 4) ? sc4 : (sc + r * SW);
                    const float w0 = sr[0], w1 = sr[1], w2 = sr[2],
                                w3 = sr[3], w4 = sr[4];
                    acc[5 * r + 0] = fmaf(f, w0, acc[5 * r + 0]);
                    acc[5 * r + 1] = fmaf(f, w1, acc[5 * r + 1]);
                    acc[5 * r + 2] = fmaf(f, w2, acc[5 * r + 2]);
                    acc[5 * r + 3] = fmaf(f, w3, acc[5 * r + 3]);
                    acc[5 * r + 4] = fmaf(f, w4, acc[5 * r + 4]);
                }
            }
        }
        // no tail barrier: double buffer + next iteration's barrier protect reuse
    }

    // inverse norms
    invnS[e0] = 1.0f / fmaxf(sqrtf(ss0), 1e-12f);
    if (has1) invnS[e1] = 1.0f / fmaxf(sqrtf(ss1), 1e-12f);
    __syncthreads();

    // epilogue: triplet margin (all indices compile-time static)
    const int cbase = (ty + 2) * SW + (tx + 2);
    const float ic = invnS[cbase];
    const int   lc = lblS[cbase];

    float pos_num = 0.0f, neg_num = 0.0f, pos_sum = 0.0f, neg_sum = 0.0f;
    #pragma unroll
    for (int di = 0; di < 5; ++di) {
        #pragma unroll
        for (int dj = 0; dj < 5; ++dj) {
            const int e = (ty + di) * SW + (tx + dj);
            const float sim = acc[di * 5 + dj] * ic * invnS[e];
            const float aff = sqrtf(fmaxf(1e-9f, 2.0f - 2.0f * sim));
            const float mf  = (lblS[e] == lc) ? 1.0f : 0.0f;
            pos_num += mf;
            neg_num += 1.0f - mf;
            pos_sum = fmaf(mf, aff, pos_sum);
            neg_sum = fmaf(1.0f - mf, aff, neg_sum);
        }
    }
    const bool boundary = (pos_num >= 4.0f) && (neg_num >= 4.0f);
    const float tri = fmaxf(0.0f,
        pos_sum / pos_num - neg_sum / fmaxf(neg_num, 1e-12f) + 0.3f);
    out[((size_t)b * Hn + (y0 + ty)) * Wn + (x0 + tx)] = boundary ? tri : 0.0f;
}

extern "C" void kernel_launch(void* const* d_in, const int* in_sizes, int n_in,
                              void* d_out, int out_size, void* d_ws, size_t ws_size,
                              hipStream_t stream) {
    const float* pred   = (const float*)d_in[0];
    const int*   target = (const int*)d_in[1];
    float*       out    = (float*)d_out;
    dim3 grid(Wn / TW, Hn / TH, Bn);   // 10 x 24 x 4 = 960 blocks
    guide_triplet_kernel<<<grid, NT, 0, stream>>>(pred, target, out);
}

// Round 7
// 71.779 us; speedup vs baseline: 4.0556x; 1.1975x over previous
//
#include <hip/hip_runtime.h>

// Problem constants (fixed by reference)
constexpr int Bn = 4, Cn = 64, Hn = 192, Wn = 640, HW = Hn * Wn;
constexpr int TH = 8, TW = 64;            // output tile per block
constexpr int SH = TH + 4, SW = TW + 4;   // 12 x 68 tile+halo
constexpr int NS = SH * SW;               // 816
constexpr int NT = 512;                   // 1 output px/thread
constexpr int CH = 4;                     // channels staged per chunk
constexpr int NCHUNK = Cn / CH;           // 16
constexpr int DR = SH - 2;                // 10 rows needing forward dots (0..9)
constexpr int ND = DR * SW;               // 680 forward-domain pixels
constexpr int NPAIR = (DR / 2) * SW;      // 340 pair-threads (2 px each)
// Arena: channel slices (2*CH*NS = 6528 w) during the loop; 12 forward-dot
// planes (12*ND = 8160 w) afterwards. Edge threads overread slices by up to
// ~2 words past 6528 (harmless garbage into never-consumed accs) - covered.
constexpr int ARENA = 12 * ND;            // 8160 floats = 32.6 KB

__global__ __launch_bounds__(NT, 4) void guide_triplet_kernel(
    const float* __restrict__ pred,
    const int*   __restrict__ target,
    float* __restrict__ out)
{
    __shared__ float arena[ARENA];
    __shared__ float invnS[NS];
    __shared__ int   lblS[NS];

    const int x0 = blockIdx.x * TW;
    const int y0 = blockIdx.y * TH;
    const int b  = blockIdx.z;

    const int tid = threadIdx.x;
    const int tx  = tid & (TW - 1);   // 0..63
    const int ty  = tid >> 6;         // 0..7

    // ---- staging geometry (2 elements/thread, 2nd partial) ----
    const int e0 = tid;
    const int e1 = tid + NT;
    const bool has1 = (e1 < NS);      // tid < 304
    const int r0 = e0 / SW, c0 = e0 % SW;
    const int r1 = e1 / SW, c1 = e1 % SW;
    const int gy0 = y0 + r0 - 2, gx0 = x0 + c0 - 2;
    const int gy1 = y0 + r1 - 2, gx1 = x0 + c1 - 2;
    const bool ok0 = (gy0 >= 0) && (gy0 < Hn) && (gx0 >= 0) && (gx0 < Wn);
    const bool ok1 = has1 && (gy1 >= 0) && (gy1 < Hn) && (gx1 >= 0) && (gx1 < Wn);
    const int off0 = gy0 * Wn + gx0;
    const int off1 = gy1 * Wn + gx1;

    // ---- labels once (pad = -1) ----
    {
        const int* tb = target + b * HW;
        lblS[e0] = ok0 ? tb[off0] : -1;
        if (has1) lblS[e1] = ok1 ? tb[off1] : -1;
    }

    // ---- forward-pair mapping: thread -> pixels (rA,pc),(rA+1,pc) ----
    const bool isPair = (tid < NPAIR);
    const int pa = tid / SW;          // 0..4
    const int pc = tid - pa * SW;     // 0..67
    const int rA = 2 * pa;            // 0,2,4,6,8

    float ss0 = 0.0f, ss1 = 0.0f;
    float accA[12], accB[12];
    #pragma unroll
    for (int i = 0; i < 12; ++i) { accA[i] = 0.0f; accB[i] = 0.0f; }

    const float* predb = pred + (size_t)b * Cn * HW;

    // prologue: chunk 0 into registers
    float ld0[CH], ld1[CH];
    #pragma unroll
    for (int cc = 0; cc < CH; ++cc) {
        ld0[cc] = ok0 ? predb[cc * HW + off0] : 0.0f;
        ld1[cc] = ok1 ? predb[cc * HW + off1] : 0.0f;
    }

    // main loop:  W(k) | sync | issue L(k+1) | C(k)
    for (int chunk = 0; chunk < NCHUNK; ++chunk) {
        float* sb = arena + (chunk & 1) * (CH * NS);

        // W(k): registers -> LDS, fold sumsq
        #pragma unroll
        for (int cc = 0; cc < CH; ++cc) {
            sb[cc * NS + e0] = ld0[cc];
            ss0 = fmaf(ld0[cc], ld0[cc], ss0);
            if (has1) {
                sb[cc * NS + e1] = ld1[cc];
                ss1 = fmaf(ld1[cc], ld1[cc], ss1);
            }
        }
        __syncthreads();

        // L(k+1): issue next chunk's loads; latency hidden under C(k)
        if (chunk + 1 < NCHUNK) {
            const float* pc_ = predb + (size_t)(chunk + 1) * CH * HW;
            #pragma unroll
            for (int cc = 0; cc < CH; ++cc) {
                ld0[cc] = ok0 ? pc_[cc * HW + off0] : 0.0f;
                ld1[cc] = ok1 ? pc_[cc * HW + off1] : 0.0f;
            }
        }

        // C(k): forward dots only - 18 LDS words + 24 FMA per channel per pair
        if (isPair) {
            #pragma unroll
            for (int cc = 0; cc < CH; ++cc) {
                const float* s0 = sb + cc * NS + rA * SW + pc;
                const float w00 = s0[0], w01 = s0[1], w02 = s0[2];
                const float* s1 = s0 + (SW - 2);
                const float w10 = s1[0], w11 = s1[1], w12 = s1[2],
                            w13 = s1[3], w14 = s1[4];
                const float* s2 = s1 + SW;
                const float w20 = s2[0], w21 = s2[1], w22 = s2[2],
                            w23 = s2[3], w24 = s2[4];
                const float* s3 = s2 + SW;
                const float w30 = s3[0], w31 = s3[1], w32 = s3[2],
                            w33 = s3[3], w34 = s3[4];
                // pixel A = (rA,pc), center w00; dirs (0,1)(0,2)(1,-2..2)(2,-2..2)
                accA[0]  = fmaf(w00, w01, accA[0]);
                accA[1]  = fmaf(w00, w02, accA[1]);
                accA[2]  = fmaf(w00, w10, accA[2]);
                accA[3]  = fmaf(w00, w11, accA[3]);
                accA[4]  = fmaf(w00, w12, accA[4]);
                accA[5]  = fmaf(w00, w13, accA[5]);
                accA[6]  = fmaf(w00, w14, accA[6]);
                accA[7]  = fmaf(w00, w20, accA[7]);
                accA[8]  = fmaf(w00, w21, accA[8]);
                accA[9]  = fmaf(w00, w22, accA[9]);
                accA[10] = fmaf(w00, w23, accA[10]);
                accA[11] = fmaf(w00, w24, accA[11]);
                // pixel B = (rA+1,pc), center w12
                accB[0]  = fmaf(w12, w13, accB[0]);
                accB[1]  = fmaf(w12, w14, accB[1]);
                accB[2]  = fmaf(w12, w20, accB[2]);
                accB[3]  = fmaf(w12, w21, accB[3]);
                accB[4]  = fmaf(w12, w22, accB[4]);
                accB[5]  = fmaf(w12, w23, accB[5]);
                accB[6]  = fmaf(w12, w24, accB[6]);
                accB[7]  = fmaf(w12, w30, accB[7]);
                accB[8]  = fmaf(w12, w31, accB[8]);
                accB[9]  = fmaf(w12, w32, accB[9]);
                accB[10] = fmaf(w12, w33, accB[10]);
                accB[11] = fmaf(w12, w34, accB[11]);
            }
        }
        // no tail barrier: double buffer + next iteration's barrier protect reuse
    }

    // ---- inverse norms (before the arena-reuse barrier) ----
    invnS[e0] = 1.0f / fmaxf(sqrtf(ss0), 1e-12f);
    if (has1) invnS[e1] = 1.0f / fmaxf(sqrtf(ss1), 1e-12f);
    __syncthreads();   // all slice reads done; invn visible

    // ---- publish forward-dot planes into the arena ----
    if (isPair) {
        const int qA = rA * SW + pc;
        const int qB = qA + SW;
        #pragma unroll
        for (int k = 0; k < 12; ++k) {
            arena[k * ND + qA] = accA[k];
            arena[k * ND + qB] = accB[k];
        }
    }
    __syncthreads();

    // ---- epilogue: assemble 25 terms per output pixel ----
    const int qp = (2 + ty) * SW + (2 + tx);
    const float ic = invnS[qp];
    const int   lc = lblS[qp];

    // self term: sim==1 (clamped) -> aff = sqrt(1e-9); always positive-class
    float pn = 1.0f, nn = 0.0f, ps = 3.16227766e-5f, ns_ = 0.0f;

    constexpr int DIRD[12] = {1, 2, SW - 2, SW - 1, SW, SW + 1, SW + 2,
                              2 * SW - 2, 2 * SW - 1, 2 * SW, 2 * SW + 1, 2 * SW + 2};
    #pragma unroll
    for (int k = 0; k < 12; ++k) {
        const int dq = DIRD[k];
        {   // forward neighbor p+d  (dot stored at p)
            const float sim = arena[k * ND + qp] * ic * invnS[qp + dq];
            const float aff = sqrtf(fmaxf(1e-9f, 2.0f - 2.0f * sim));
            const float mf  = (lblS[qp + dq] == lc) ? 1.0f : 0.0f;
            pn += mf; nn += 1.0f - mf;
            ps = fmaf(mf, aff, ps); ns_ = fmaf(1.0f - mf, aff, ns_);
        }
        {   // backward neighbor p-d  (dot stored at p-d)
            const float sim = arena[k * ND + qp - dq] * ic * invnS[qp - dq];
            const float aff = sqrtf(fmaxf(1e-9f, 2.0f - 2.0f * sim));
            const float mf  = (lblS[qp - dq] == lc) ? 1.0f : 0.0f;
            pn += mf; nn += 1.0f - mf;
            ps = fmaf(mf, aff, ps); ns_ = fmaf(1.0f - mf, aff, ns_);
        }
    }
    const bool boundary = (pn >= 4.0f) && (nn >= 4.0f);
    const float tri = fmaxf(0.0f, ps / pn - ns_ / fmaxf(nn, 1e-12f) + 0.3f);
    out[((size_t)b * Hn + (y0 + ty)) * Wn + (x0 + tx)] = boundary ? tri : 0.0f;
}

extern "C" void kernel_launch(void* const* d_in, const int* in_sizes, int n_in,
                              void* d_out, int out_size, void* d_ws, size_t ws_size,
                              hipStream_t stream) {
    const float* pred   = (const float*)d_in[0];
    const int*   target = (const int*)d_in[1];
    float*       out    = (float*)d_out;
    dim3 grid(Wn / TW, Hn / TH, Bn);   // 10 x 24 x 4 = 960 blocks
    guide_triplet_kernel<<<grid, NT, 0, stream>>>(pred, target, out);
}